// Round 11
// baseline (373.716 us; speedup 1.0000x reference)
//
#include <hip/hip_runtime.h>

#define DD 128
#define PARTS 8
#define SLICES 16
#define PBINS 6272    // >= ceil(N/PARTS) = 6250
#define FB (PARTS * SLICES)

typedef __bf16 bf16x8 __attribute__((ext_vector_type(8)));
typedef float f32x4 __attribute__((ext_vector_type(4)));

static __device__ __forceinline__ unsigned short f2bf(float f) {
    unsigned int u = __float_as_uint(f);
    u += 0x7FFF + ((u >> 16) & 1);   // round-to-nearest-even
    return (unsigned short)(u >> 16);
}

// ---------------- count: atomic-free partitioned LDS histogram ----------------
// block (p,c) reads edge-slice c, filters dst to partition p, LDS-atomic counts,
// writes partial[c][bin] coalesced. blocks >= FB do the one-time W f32->bf16.

__global__ __launch_bounds__(1024) void k_count(
    const int* __restrict__ dst, int* __restrict__ partial,
    const float* __restrict__ W1, const float* __restrict__ W2,
    unsigned short* __restrict__ wbf, int N, int E)
{
    const int bid = blockIdx.x;
    const int tid = threadIdx.x;
    if (bid >= FB) {
        // W conversion: 8 blocks x 1024 threads x 1 float4 = 32768 elems (W1+W2)
        int i = (bid - FB) * 1024 + tid;   // 0..8191
        float4 v = (i < 4096) ? ((const float4*)W1)[i] : ((const float4*)W2)[i - 4096];
        ushort4 b;
        b.x = f2bf(v.x); b.y = f2bf(v.y); b.z = f2bf(v.z); b.w = f2bf(v.w);
        *(ushort4*)&wbf[(size_t)i * 4] = b;
        return;
    }

    __shared__ int hist[PBINS];
    const int p     = bid & (PARTS - 1);
    const int c     = bid / PARTS;
    const int psize = (N + PARTS - 1) / PARTS;
    const int lo    = p * psize;

    for (int t = tid; t < psize; t += 1024) hist[t] = 0;
    __syncthreads();

    const int sl = (E + SLICES - 1) / SLICES;
    const int e0 = c * sl;
    const int e1 = (e0 + sl < E) ? e0 + sl : E;

    int e = e0 + tid * 4;
    for (; e + 3 < e1; e += 4096) {
        int4 d = *(const int4*)&dst[e];
        unsigned t0 = (unsigned)(d.x - lo), t1 = (unsigned)(d.y - lo);
        unsigned t2 = (unsigned)(d.z - lo), t3 = (unsigned)(d.w - lo);
        if (t0 < (unsigned)psize) atomicAdd(&hist[t0], 1);
        if (t1 < (unsigned)psize) atomicAdd(&hist[t1], 1);
        if (t2 < (unsigned)psize) atomicAdd(&hist[t2], 1);
        if (t3 < (unsigned)psize) atomicAdd(&hist[t3], 1);
    }
    if (e < e1) {                      // straddling tail (none when sl % 4 == 0)
        for (int k = e; k < e1; ++k) {
            unsigned t0 = (unsigned)(dst[k] - lo);
            if (t0 < (unsigned)psize) atomicAdd(&hist[t0], 1);
        }
    }
    __syncthreads();

    int* op = partial + (size_t)c * N;
    for (int t = tid; t < psize; t += 1024) {
        int g = lo + t;
        if (g < N) op[g] = hist[t];
    }
}

// ---------------- scan phase 1: slice-prefix (in place), block-local scan, dinv ----

__global__ __launch_bounds__(1024) void k_scan1(int* __restrict__ partial,
                                                int* __restrict__ rp,
                                                float* __restrict__ dinv,
                                                int* __restrict__ bsum, int N) {
    __shared__ int wsum[16];
    const int tid = threadIdx.x, lane = tid & 63, wid = tid >> 6;
    const int i = blockIdx.x * 1024 + tid;
    int v = 0;
    if (i < N) {
        int run = 0;
#pragma unroll
        for (int c = 0; c < SLICES; ++c) {
            int t = partial[(size_t)c * N + i];
            partial[(size_t)c * N + i] = run;   // exclusive prefix over slices
            run += t;
        }
        v = run;                                // total in-degree
    }
    int s = v;
    for (int off = 1; off < 64; off <<= 1) {
        int t = __shfl_up(s, off, 64);
        if (lane >= off) s += t;
    }
    if (lane == 63) wsum[wid] = s;
    __syncthreads();
    int woff = 0, total = 0;
#pragma unroll
    for (int w2 = 0; w2 < 16; ++w2) {
        int t = wsum[w2];
        if (w2 < wid) woff += t;
        total += t;
    }
    if (i < N) {
        rp[i + 1] = woff + s;                 // block-local inclusive
        dinv[i] = rsqrtf((float)(v + 1));     // +1 self-loop
    }
    if (tid == 0) bsum[blockIdx.x] = total;
}

// scan phase 2: add exclusive prefix of block sums.
__global__ __launch_bounds__(1024) void k_scan2(const int* __restrict__ bsum,
                                                int* __restrict__ rp, int N) {
    __shared__ int boff_s;
    const int tid = threadIdx.x;
    if (tid < 64) {
        int v = (tid < (int)blockIdx.x) ? bsum[tid] : 0;   // nb <= 49 < 64
        for (int off = 32; off > 0; off >>= 1) v += __shfl_down(v, off, 64);
        if (tid == 0) boff_s = v;
    }
    __syncthreads();
    const int i = blockIdx.x * 1024 + tid;
    if (i < N) rp[i + 1] += boff_s;
    if (i == 0) rp[0] = 0;
}

// ---------------- mid: CSR fill (blocks [0, FB), zero global atomics) || gemm ----
// fill block (p,c): LDS cursor = rp[g] + slice-prefix; stream slice edges; place
// owned edges via LDS atomicAdd -> disjoint csr ranges, race-free.

__global__ __launch_bounds__(512) void k_mid(
    const float* __restrict__ x0, const float* __restrict__ x1,
    const float* __restrict__ x2, const float* __restrict__ x3,
    const unsigned short* __restrict__ wbf,
    unsigned short* __restrict__ h,
    const int* __restrict__ ei, const int* __restrict__ rp,
    const float* __restrict__ dinv, const int* __restrict__ partial,
    int2* __restrict__ csr, int N, int E)
{
    __shared__ __align__(16) char smem_raw[128 * 136 * 2];  // 34816 B union
    const int bid = blockIdx.x;
    const int tid = threadIdx.x;

    if (bid < FB) {
        // ---- fill ----
        int* curs = (int*)smem_raw;           // PBINS*4 = 25088 B <= 34816
        const int p     = bid & (PARTS - 1);
        const int c     = bid / PARTS;
        const int psize = (N + PARTS - 1) / PARTS;
        const int lo    = p * psize;

        for (int t = tid; t < psize; t += 512) {
            int g = lo + t;
            curs[t] = (g < N) ? rp[g] + partial[(size_t)c * N + g] : 0;
        }
        __syncthreads();

        const int sl = (E + SLICES - 1) / SLICES;
        const int e0 = c * sl;
        const int e1 = (e0 + sl < E) ? e0 + sl : E;

        int e = e0 + tid * 4;
        for (; e + 3 < e1; e += 2048) {
            int4 d = *(const int4*)&ei[E + e];
            int4 s = *(const int4*)&ei[e];
            unsigned t0 = (unsigned)(d.x - lo), t1 = (unsigned)(d.y - lo);
            unsigned t2 = (unsigned)(d.z - lo), t3 = (unsigned)(d.w - lo);
            if (t0 < (unsigned)psize) {
                int pos = atomicAdd(&curs[t0], 1);
                csr[pos] = make_int2(s.x, __float_as_int(dinv[s.x]));
            }
            if (t1 < (unsigned)psize) {
                int pos = atomicAdd(&curs[t1], 1);
                csr[pos] = make_int2(s.y, __float_as_int(dinv[s.y]));
            }
            if (t2 < (unsigned)psize) {
                int pos = atomicAdd(&curs[t2], 1);
                csr[pos] = make_int2(s.z, __float_as_int(dinv[s.z]));
            }
            if (t3 < (unsigned)psize) {
                int pos = atomicAdd(&curs[t3], 1);
                csr[pos] = make_int2(s.w, __float_as_int(dinv[s.w]));
            }
        }
        if (e < e1) {                  // straddling tail (none when sl % 4 == 0)
            for (int k = e; k < e1; ++k) {
                int dk = ei[E + k];
                unsigned t0 = (unsigned)(dk - lo);
                if (t0 < (unsigned)psize) {
                    int sk = ei[k];
                    int pos = atomicAdd(&curs[t0], 1);
                    csr[pos] = make_int2(sk, __float_as_int(dinv[sk]));
                }
            }
        }
        return;
    }

    // ---- gemm ----
    const int gb = bid - FB;
    const int m  = gb & 3;
    const float* x = (m == 0) ? x0 : (m == 1) ? x1 : (m == 2) ? x2 : x3;
    const unsigned short* Wg = wbf + (size_t)(m & 1) * 128 * 128;  // m=0,2->W1; 1,3->W2
    unsigned short* smem = (unsigned short*)smem_raw;   // Ws view / epilogue view

    const int n0   = (gb >> 2) * 128;
    const int w    = tid >> 6;       // 8 waves: rows w*16..w*16+15
    const int lane = tid & 63;
    const int am   = lane & 15;
    const int aq   = lane >> 4;
    const int r0   = w * 16;

    // A: direct global -> regs. Row clamped for OOB: garbage lands only in
    // C rows >= N, which are never stored.
    int arow = n0 + r0 + am; if (arow > N - 1) arow = N - 1;
    const float* xr = x + (size_t)arow * DD + aq * 8;
    float4 a0[4], a1[4];
#pragma unroll
    for (int q = 0; q < 4; ++q) {
        a0[q] = *(const float4*)(xr + q * 32);
        a1[q] = *(const float4*)(xr + q * 32 + 4);
    }

    // stage W: 16B copies with swizzle (uint4 index t -> t ^ ((t>>4)&7))
#pragma unroll
    for (int t = tid; t < 2048; t += 512)
        ((uint4*)smem)[t ^ ((t >> 4) & 7)] = ((const uint4*)Wg)[t];
    __syncthreads();

    // convert A to bf16 fragments (vmcnt wait lands here, after W staging)
    bf16x8 afr[4];
#pragma unroll
    for (int q = 0; q < 4; ++q) {
        afr[q][0] = (__bf16)a0[q].x; afr[q][1] = (__bf16)a0[q].y;
        afr[q][2] = (__bf16)a0[q].z; afr[q][3] = (__bf16)a0[q].w;
        afr[q][4] = (__bf16)a1[q].x; afr[q][5] = (__bf16)a1[q].y;
        afr[q][6] = (__bf16)a1[q].z; afr[q][7] = (__bf16)a1[q].w;
    }

    f32x4 acc[8] = {};
#pragma unroll
    for (int q = 0; q < 4; ++q) {
        const int kc = q * 32 + aq * 8;
#pragma unroll
        for (int ct = 0; ct < 8; ++ct) {
            bf16x8 bf = *(const bf16x8*)&smem[(ct * 16 + am) * 128 +
                                              (kc ^ ((am & 7) << 3))];
            acc[ct] = __builtin_amdgcn_mfma_f32_16x16x32_bf16(afr[q], bf, acc[ct], 0, 0, 0);
        }
    }
    __syncthreads();   // all waves done reading Ws view

    // single-pass epilogue into 128x136 view
    // C/D layout: col = lane&15, row = (lane>>4)*4 + i
    const int cc = lane & 15;
    const int rr = (lane >> 4) * 4;
#pragma unroll
    for (int ct = 0; ct < 8; ++ct)
#pragma unroll
        for (int i = 0; i < 4; ++i)
            smem[(r0 + rr + i) * 136 + ct * 16 + cc] = f2bf(acc[ct][i]);
    __syncthreads();

    // coalesced store into interleaved layout: h[(n*4 + m)*128 + c]; 4 x 16B per thread
#pragma unroll
    for (int k = 0; k < 4; ++k) {
        int f = k * 512 + tid;             // 128 rows x 16 chunks
        int row2 = f >> 4, ch = f & 15;
        int n = n0 + row2;
        if (n < N)
            *(uint4*)(h + ((size_t)n * 4 + m) * DD + ch * 8) =
                *(const uint4*)&smem[row2 * 136 + ch * 8];
    }
}

// ---------------- aggregation: gather by dst via CSR (interleaved bf16 h) -----
// ONE WAVE PER NODE (4 nodes/block). Split into TWO dispatches over node ranges
// (diagnostic: surfaces the true #2 kernel in the profile top-5; traffic identical).

static __device__ __forceinline__ void acc8(float* a, uint4 v, float wt) {
    a[0] += __uint_as_float(v.x << 16) * wt;
    a[1] += __uint_as_float(v.x & 0xffff0000u) * wt;
    a[2] += __uint_as_float(v.y << 16) * wt;
    a[3] += __uint_as_float(v.y & 0xffff0000u) * wt;
    a[4] += __uint_as_float(v.z << 16) * wt;
    a[5] += __uint_as_float(v.z & 0xffff0000u) * wt;
    a[6] += __uint_as_float(v.w << 16) * wt;
    a[7] += __uint_as_float(v.w & 0xffff0000u) * wt;
}

__global__ __launch_bounds__(256) void k_gather(
    const int* __restrict__ rp, const int2* __restrict__ csr,
    const float* __restrict__ dinv, const unsigned short* __restrict__ h,
    const float* __restrict__ b1, const float* __restrict__ b2,
    float* __restrict__ out, int N, int nbase)
{
    const int n = nbase + blockIdx.x * 4 + (threadIdx.x >> 6);
    if (n >= N) return;
    const int lane = threadIdx.x & 63;
    const int m    = lane >> 4;          // matrix 0..3
    const int c    = (lane & 15) * 8;    // col base (8 floats)
    const size_t off = (size_t)lane * 8; // ushort offset within 512-wide node row

    const float dn = dinv[n];
    float a[8];

    // self-loop + bias
    {
        const float sn = dn * dn;
        const float* bb = (m & 1) ? b2 : b1;
        uint4 hv = *(const uint4*)(h + (size_t)n * 512 + off);
        float4 bv0 = *(const float4*)(bb + c);
        float4 bv1 = *(const float4*)(bb + c + 4);
        a[0] = bv0.x; a[1] = bv0.y; a[2] = bv0.z; a[3] = bv0.w;
        a[4] = bv1.x; a[5] = bv1.y; a[6] = bv1.z; a[7] = bv1.w;
        acc8(a, hv, sn);
    }

    int jb = rp[n];
    const int j1 = rp[n + 1];

    for (; jb + 7 < j1; jb += 8) {
        int2 e0 = csr[jb],     e1 = csr[jb + 1], e2 = csr[jb + 2], e3 = csr[jb + 3];
        int2 e4 = csr[jb + 4], e5 = csr[jb + 5], e6 = csr[jb + 6], e7 = csr[jb + 7];
        float w0 = __int_as_float(e0.y) * dn, w1 = __int_as_float(e1.y) * dn,
              w2 = __int_as_float(e2.y) * dn, w3 = __int_as_float(e3.y) * dn,
              w4 = __int_as_float(e4.y) * dn, w5 = __int_as_float(e5.y) * dn,
              w6 = __int_as_float(e6.y) * dn, w7 = __int_as_float(e7.y) * dn;
        uint4 v0 = *(const uint4*)(h + (size_t)e0.x * 512 + off);
        uint4 v1 = *(const uint4*)(h + (size_t)e1.x * 512 + off);
        uint4 v2 = *(const uint4*)(h + (size_t)e2.x * 512 + off);
        uint4 v3 = *(const uint4*)(h + (size_t)e3.x * 512 + off);
        uint4 v4 = *(const uint4*)(h + (size_t)e4.x * 512 + off);
        uint4 v5 = *(const uint4*)(h + (size_t)e5.x * 512 + off);
        uint4 v6 = *(const uint4*)(h + (size_t)e6.x * 512 + off);
        uint4 v7 = *(const uint4*)(h + (size_t)e7.x * 512 + off);
        acc8(a, v0, w0); acc8(a, v1, w1); acc8(a, v2, w2); acc8(a, v3, w3);
        acc8(a, v4, w4); acc8(a, v5, w5); acc8(a, v6, w6); acc8(a, v7, w7);
    }
    if (jb < j1) {               // one masked batch covers the remainder
        const int last = j1 - 1;
#pragma unroll
        for (int k = 0; k < 8; ++k) {
            int idx = jb + k;
            int2 e = csr[idx <= last ? idx : last];   // clamped: line is hot
            float wt = (idx <= last) ? __int_as_float(e.y) * dn : 0.f;
            uint4 v = *(const uint4*)(h + (size_t)e.x * 512 + off);
            acc8(a, v, wt);
        }
    }

    float* po = out + ((size_t)m * N + n) * DD + c;
    f32x4 r0, r1;
    r0.x = a[0]; r0.y = a[1]; r0.z = a[2]; r0.w = a[3];
    r1.x = a[4]; r1.y = a[5]; r1.z = a[6]; r1.w = a[7];
    // streaming store: out is never re-read -> keep L2/L3 for h gathers
    __builtin_nontemporal_store(r0, (f32x4*)po);
    __builtin_nontemporal_store(r1, (f32x4*)(po + 4));
}

// ---------------- launch ----------------

extern "C" void kernel_launch(void* const* d_in, const int* in_sizes, int n_in,
                              void* d_out, int out_size, void* d_ws, size_t ws_size,
                              hipStream_t stream) {
    const float* x0 = (const float*)d_in[0];
    const float* x1 = (const float*)d_in[1];
    const float* x2 = (const float*)d_in[2];
    const float* x3 = (const float*)d_in[3];
    const int*   ei = (const int*)d_in[4];
    const float* W1 = (const float*)d_in[5];
    const float* b1 = (const float*)d_in[6];
    const float* W2 = (const float*)d_in[7];
    const float* b2 = (const float*)d_in[8];
    float* out = (float*)d_out;

    const int N = in_sizes[0] / DD;   // 50000
    const int E = in_sizes[4] / 2;    // 800000

    // workspace layout
    int*   rp   = (int*)d_ws;                        // 65536 (needs N+1)
    float* dinv = (float*)(rp + 65536);              // 65536
    int*   bsum = (int*)(dinv + 65536);              // 256
    unsigned short* wbf = (unsigned short*)(bsum + 256);  // 2*128*128 bf16 = 64 KB
    int2*  csr  = (int2*)(wbf + 2 * 128 * 128);      // E int2 {src, dinv[src]}
    unsigned short* h = (unsigned short*)(csr + E);  // interleaved [N][4][128] bf16 = 51.2 MB

    // slice-partial histograms live in d_out as scratch (SLICES*N ints = 3.2 MB
    // << out_size; dead before k_gather rewrites every byte of out)
    int* partial = (int*)d_out;

    const int nscan = (N + 1023) / 1024;             // 49
    const int GB    = ((N + 127) / 128) * 4;         // gemm blocks = 1564

    const int half  = ((N / 2) + 3) & ~3;            // 25000 (multiple of 4)
    const int gb1   = half / 4;                      // 6250 blocks, nodes [0, half)
    const int gb2   = (N - half + 3) / 4;            // nodes [half, N)

    k_count<<<FB + 8, 1024, 0, stream>>>(ei + E, partial, W1, W2, wbf, N, E);
    k_scan1<<<nscan, 1024, 0, stream>>>(partial, rp, dinv, bsum, N);
    k_scan2<<<nscan, 1024, 0, stream>>>(bsum, rp, N);
    k_mid  <<<FB + GB, 512, 0, stream>>>(x0, x1, x2, x3, wbf, h,
                                         ei, rp, dinv, partial, csr, N, E);
    k_gather<<<gb1, 256, 0, stream>>>(rp, csr, dinv, h, b1, b2, out, N, 0);
    k_gather<<<gb2, 256, 0, stream>>>(rp, csr, dinv, h, b1, b2, out, N, half);
}